// Round 15
// baseline (283.838 us; speedup 1.0000x reference)
//
#include <hip/hip_runtime.h>
#include <stdint.h>

#define T_STEPS 256
#define F_IN 64
#define L2E 1.44269504f

typedef __bf16 bf16x8 __attribute__((ext_vector_type(8)));
typedef float f32x4 __attribute__((ext_vector_type(4)));
typedef uint32_t u32;
typedef uint32_t u32x4 __attribute__((ext_vector_type(4)));

static __device__ __forceinline__ u32 pk2(float lo, float hi) {
    unsigned short a = __builtin_bit_cast(unsigned short, (__bf16)lo);
    unsigned short b = __builtin_bit_cast(unsigned short, (__bf16)hi);
    return (u32)a | ((u32)b << 16);
}

// One wave owns one 16-row tile, all 256 steps. NO barriers, NO LDS AT ALL.
// x supply = pure-register ring, 8 steps deep (~28KB/wave sustained in flight
// vs 8-16KB in every prior round -> Little's-law BW unblock test).
// Per-lane loads: lane (cl,g4) reads row cl, features g4*8+{0..7} and
// 32+g4*8+{0..7} -> exactly the B-frag elements it consumes (R1-proven).
// h exchange = R13-proven select-after-shuffle. accx pipeline = R11-proven.
// Transposed MFMA: gates^T[128][16] = (S.W^T)[128][96] @ [x|h]^T[96][16]
__global__ __launch_bounds__(256, 1)
void lstm_fused(const float* __restrict__ x,
                const float* __restrict__ Wl,   // [96][128]
                const float* __restrict__ bl,   // [128]
                const float* __restrict__ Wd,   // [32]
                const float* __restrict__ bd,   // [1]
                float* __restrict__ out)        // [B]
{
    const int lane = threadIdx.x & 63;
    const int wid  = threadIdx.x >> 6;
    const int cl   = lane & 15;
    const int g4   = lane >> 4;
    const int rowBase = blockIdx.x * 64 + wid * 16;

    // gate-type scale per tile q (q=0,1: i; 2,3: j; 4,5: f; 6,7: o)
#define GSC(q) (((q) >> 1) == 1 ? -2.0f * L2E : -L2E)

    // ---- 24 pre-scaled W^T A-fragments (standard K-row order, R13-proven) ----
    bf16x8 wfrag[3][8];
#pragma unroll
    for (int kc = 0; kc < 3; ++kc) {
#pragma unroll
        for (int q = 0; q < 8; ++q) {
            bf16x8 v;
#pragma unroll
            for (int j = 0; j < 8; ++j)
                v[j] = (__bf16)(GSC(q) * Wl[(kc * 32 + g4 * 8 + j) * 128 + q * 16 + cl]);
            wfrag[kc][q] = v;
        }
    }

    // ---- pre-scaled bias as MFMA C-init ----
    f32x4 biasf[8];
#pragma unroll
    for (int q = 0; q < 8; ++q) {
#pragma unroll
        for (int r = 0; r < 4; ++r) {
            const int gate = q * 16 + g4 * 4 + r;
            biasf[q][r] = GSC(q) * (bl[gate] + ((q >> 1) == 2 ? 1.0f : 0.0f));
        }
    }
    const float bd0 = bd[0];
    float wdl[4], wdh[4];
#pragma unroll
    for (int r = 0; r < 4; ++r) {
        wdl[r] = Wd[4 * g4 + r];
        wdh[r] = Wd[16 + 4 * g4 + r];
    }

    // lane-private row pointer: row cl of this tile, feature base g4*8
    const float* xrow = x + (size_t)(rowBase + cl) * (size_t)(T_STEPS * F_IN)
                          + (size_t)(g4 * 8);

    // ---- register ring: 8 step-slots x 4 f32x4 (statically indexed only) ----
    f32x4 xa[8], xb[8], xc[8], xd[8];

#define LOADS(S, TT) do {                                                      \
    const float* p = xrow + (size_t)(TT) * F_IN;                               \
    xa[S] = *(const f32x4*)(p);                                                \
    xb[S] = *(const f32x4*)(p + 4);                                            \
    xc[S] = *(const f32x4*)(p + 32);                                           \
    xd[S] = *(const f32x4*)(p + 36);                                           \
} while (0)

    // shuffle-exchange constants (R13-proven)
    const int srcA = cl + 32 * (g4 & 1);
    const int srcB = srcA + 16;
    const int sel  = g4 >> 1;

    f32x4 csl = {0.f, 0.f, 0.f, 0.f};   // c' = -2*L2E*c, units 4g4+r
    f32x4 csh = {0.f, 0.f, 0.f, 0.f};   // units 16+4g4+r
    f32x4 hlv, hhv;
    u32x4 ahw = {0u, 0u, 0u, 0u};       // h0 = 0
    f32x4 accx[8];

#define CELL(AI, AJ, AF, AO, CS, HV) do {                                      \
    _Pragma("unroll")                                                          \
    for (int r = 0; r < 4; ++r) {                                              \
        float I  = __builtin_amdgcn_exp2f((AI)[r]);                            \
        float J  = __builtin_amdgcn_exp2f((AJ)[r]);                            \
        float Fv = __builtin_amdgcn_exp2f((AF)[r]);                            \
        float O  = __builtin_amdgcn_exp2f((AO)[r]);                            \
        float t3 = (1.0f + I) * (1.0f + J);                                    \
        float uu = 1.0f + Fv;                                                  \
        float np = __builtin_fmaf(J, 2.0f * L2E, -2.0f * L2E);                 \
        float r1 = __builtin_amdgcn_rcpf(t3 * uu);                             \
        float nm = __builtin_fmaf((CS)[r], t3, np * uu);                       \
        float cp = nm * r1;                                                    \
        float C  = __builtin_amdgcn_exp2f(cp);                                 \
        float r2 = __builtin_amdgcn_rcpf((1.0f + C) * (1.0f + O));             \
        (HV)[r] = (1.0f - C) * r2;                                             \
        (CS)[r] = cp;                                                          \
    }                                                                          \
} while (0)

    // x-gate precompute for the step held in ring slot S (8 MFMAs into accx)
#define XGATES(S) do {                                                         \
    bf16x8 ax0, ax1;                                                           \
    _Pragma("unroll")                                                          \
    for (int j = 0; j < 4; ++j) {                                              \
        ax0[j]     = (__bf16)xa[S][j];                                         \
        ax0[4 + j] = (__bf16)xb[S][j];                                         \
        ax1[j]     = (__bf16)xc[S][j];                                         \
        ax1[4 + j] = (__bf16)xd[S][j];                                         \
    }                                                                          \
    _Pragma("unroll")                                                          \
    for (int q = 0; q < 8; ++q) {                                              \
        f32x4 a = __builtin_amdgcn_mfma_f32_16x16x32_bf16(wfrag[0][q], ax0, biasf[q], 0, 0, 0); \
        accx[q] = __builtin_amdgcn_mfma_f32_16x16x32_bf16(wfrag[1][q], ax1, a, 0, 0, 0);        \
    }                                                                          \
} while (0)

    // critical chain for one step: h-MFMA on accx, cell, pack, shuffle-exchange
#define CHAIN() do {                                                           \
    bf16x8 ah = __builtin_bit_cast(bf16x8, ahw);                               \
    f32x4 acc[8];                                                              \
    _Pragma("unroll")                                                          \
    for (int q = 0; q < 8; ++q)                                                \
        acc[q] = __builtin_amdgcn_mfma_f32_16x16x32_bf16(wfrag[2][q], ah, accx[q], 0, 0, 0); \
    CELL(acc[0], acc[2], acc[4], acc[6], csl, hlv);                            \
    CELL(acc[1], acc[3], acc[5], acc[7], csh, hhv);                            \
    u32 W0 = pk2(hlv[0], hlv[1]);                                              \
    u32 W1 = pk2(hlv[2], hlv[3]);                                              \
    u32 W2 = pk2(hhv[0], hhv[1]);                                              \
    u32 W3 = pk2(hhv[2], hhv[3]);                                              \
    int A0 = __shfl((int)W0, srcA, 64), A1 = __shfl((int)W1, srcA, 64);        \
    int A2 = __shfl((int)W2, srcA, 64), A3 = __shfl((int)W3, srcA, 64);        \
    int B0 = __shfl((int)W0, srcB, 64), B1 = __shfl((int)W1, srcB, 64);        \
    int B2 = __shfl((int)W2, srcB, 64), B3 = __shfl((int)W3, srcB, 64);        \
    ahw[0] = (u32)(sel ? A2 : A0);                                             \
    ahw[1] = (u32)(sel ? A3 : A1);                                             \
    ahw[2] = (u32)(sel ? B2 : B0);                                             \
    ahw[3] = (u32)(sel ? B3 : B1);                                             \
} while (0)

    // ---- prologue: fill ring with steps 0..7; x-gates for step 0 ----
    LOADS(0, 0); LOADS(1, 1); LOADS(2, 2); LOADS(3, 3);
    LOADS(4, 4); LOADS(5, 5); LOADS(6, 6); LOADS(7, 7);
    XGATES(0);

    // steady state: slot s reloaded for step t+s+8, consumed 7 sub-steps later.
#pragma unroll 1
    for (int t = 0; t < T_STEPS - 8; t += 8) {
        CHAIN(); LOADS(0, t +  8); XGATES(1);
        CHAIN(); LOADS(1, t +  9); XGATES(2);
        CHAIN(); LOADS(2, t + 10); XGATES(3);
        CHAIN(); LOADS(3, t + 11); XGATES(4);
        CHAIN(); LOADS(4, t + 12); XGATES(5);
        CHAIN(); LOADS(5, t + 13); XGATES(6);
        CHAIN(); LOADS(6, t + 14); XGATES(7);
        CHAIN(); LOADS(7, t + 15); XGATES(0);
    }
    // final 8 steps (t = 248..255): no more loads
    CHAIN(); XGATES(1);
    CHAIN(); XGATES(2);
    CHAIN(); XGATES(3);
    CHAIN(); XGATES(4);
    CHAIN(); XGATES(5);
    CHAIN(); XGATES(6);
    CHAIN(); XGATES(7);
    CHAIN();
#undef CHAIN
#undef XGATES
#undef CELL
#undef LOADS

    // ---- epilogue: out[b] = ELU(sum_u h[u]*Wd[u] + bd) ----
    float v = 0.f;
#pragma unroll
    for (int r = 0; r < 4; ++r) {
        v = __builtin_fmaf(hlv[r], wdl[r], v);
        v = __builtin_fmaf(hhv[r], wdh[r], v);
    }
    v += __shfl_xor(v, 16, 64);
    v += __shfl_xor(v, 32, 64);
    if (lane < 16) {
        float z = v + bd0;
        out[rowBase + lane] = z > 0.f ? z : (__expf(z) - 1.0f);
    }
}

extern "C" void kernel_launch(void* const* d_in, const int* in_sizes, int n_in,
                              void* d_out, int out_size, void* d_ws, size_t ws_size,
                              hipStream_t stream) {
    const float* x  = (const float*)d_in[0];
    const float* Wl = (const float*)d_in[1];
    const float* bl = (const float*)d_in[2];
    const float* Wd = (const float*)d_in[3];
    const float* bd = (const float*)d_in[4];
    float* out = (float*)d_out;

    const int rows = out_size;              // B = 16384
    const int grid = (rows + 63) / 64;      // 64 rows per 256-thread block (4 waves x 16)
    hipLaunchKernelGGL(lstm_fused, dim3(grid), dim3(256), 0, stream,
                       x, Wl, bl, Wd, bd, out);
}